// Round 16
// baseline (301.491 us; speedup 1.0000x reference)
//
#include <hip/hip_runtime.h>
#include <hip/hip_bf16.h>

#define N_NODES 10000
#define N_EDGES 320000
#define N_REL   460
#define N_BASES 30
#define DIM     200
#define KZ      6016   // 30*200=6000 padded to multiple of 32
#define KT      6240   // KZ + 224 (self-term columns appended)
#define NSTEPS  195    // KT/32
#define NTILES  157    // ceil(10000/64)
#define NFRAG   16     // col fragments of 16 (13 real, 3 zero-padded)
#define KSPLIT  6
#define TKELEM  2048   // ASW elements per (tile,kstep): 4 sub x 16 rows x 32 cols

#define PREP_B  (NFRAG * NSTEPS * 512)   // 1597440
#define PREP_X  (N_NODES * 224)          // 2240000
#define PREP_O  (N_NODES * DIM)          // 2000000
#define PREP_C  (N_REL * 16)             // 7360
#define PREP_TOTAL (PREP_B + PREP_X + PREP_O + PREP_C)

using short8  = __attribute__((ext_vector_type(8))) short;
using floatx4 = __attribute__((ext_vector_type(4))) float;

__device__ __forceinline__ unsigned short f2bf(float f) {
    union { float f; unsigned u; } v; v.f = f;
    unsigned u = v.u;
    return (unsigned short)((u + 0x7fffu + ((u >> 16) & 1u)) >> 16);
}

__device__ __forceinline__ short8 pack8(const unsigned short* u) {
    union { unsigned short s[8]; short8 v; } p;
#pragma unroll
    for (int i = 0; i < 8; ++i) p.s[i] = u[i];
    return p.v;
}

// ASW v3: 64-row tiles. Element (node n, col c):
//   t=n>>6, sub=(n>>4)&3, rl=n&15; kk=c>>5, w=c&31
//   idx = (t*195+kk)*2048 + sub*512 + rl*32 + w
__device__ __forceinline__ size_t asw_idx(int n, int c) {
    int t = n >> 6, sub = (n >> 4) & 3, rl = n & 15;
    int kk = c >> 5, w = c & 31;
    return (size_t)(t * NSTEPS + kk) * TKELEM + sub * 512 + rl * 32 + w;
}

// ---------------- sort-by-target (counting sort) ----------------

__global__ void hist_kernel(const int* tgt, int* deg) {
    int e = blockIdx.x * blockDim.x + threadIdx.x;
    if (e < N_EDGES) atomicAdd(&deg[tgt[e]], 1);
}

__global__ __launch_bounds__(1024) void scan_kernel(const int* deg, int* starts,
                                                    int* cursor, float* dinv) {
    __shared__ int part[1024];
    int tid = threadIdx.x;
    const int PER = (N_NODES + 1023) / 1024;  // 10
    int base = tid * PER;
    int s = 0;
    for (int i = 0; i < PER; ++i) { int idx = base + i; if (idx < N_NODES) s += deg[idx]; }
    part[tid] = s; __syncthreads();
    for (int off = 1; off < 1024; off <<= 1) {
        int v = (tid >= off) ? part[tid - off] : 0;
        __syncthreads();
        part[tid] += v;
        __syncthreads();
    }
    int run = (tid > 0) ? part[tid - 1] : 0;
    for (int i = 0; i < PER; ++i) {
        int idx = base + i;
        if (idx < N_NODES) {
            int d = deg[idx];
            starts[idx] = run; cursor[idx] = run;
            dinv[idx] = 1.0f / (float)(d > 0 ? d : 1);
            run += d;
        }
    }
    if (tid == 1023) starts[N_NODES] = part[1023];
}

__global__ void scatter_kernel(const int* src, const int* tgt, const int* etype,
                               int* cursor, int2* sedge) {
    int e = blockIdx.x * blockDim.x + threadIdx.x;
    if (e < N_EDGES) {
        int t = tgt[e];
        int pos = atomicAdd(&cursor[t], 1);
        sedge[pos] = make_int2(src[e], etype[e]);
    }
}

// ---------------- merged operand prep ----------------
// Range 0 [0,PREP_B):  BSW fragment-order B (weights + self_weight cols)
// Range 1 [..+PREP_X): Xbf = bf16(x), ASW self cols = bf16(max(deg,1)*x)
// Range 2 [..+PREP_O): out = bias (accumulation base for gemm atomics)
// Range 3 [..+PREP_C): Cpair bf16 coeff pairs

__global__ void prep_kernel(const float* __restrict__ weight, const float* __restrict__ sw,
                            const float* __restrict__ x, const float* __restrict__ coeff,
                            const float* __restrict__ bias, const int* __restrict__ deg,
                            unsigned short* __restrict__ BSW, unsigned short* __restrict__ Xbf,
                            unsigned short* __restrict__ ASW, float* __restrict__ out,
                            unsigned int* __restrict__ Cpair) {
    int idx = blockIdx.x * blockDim.x + threadIdx.x;
    if (idx < PREP_B) {
        int f = idx / (NSTEPS * 512);
        int rem = idx - f * (NSTEPS * 512);
        int kk = rem / 512;
        int e = rem - kk * 512;
        int l = e >> 3, j = e & 7;
        int rB = f * 16 + (l & 15);
        int k  = kk * 32 + (l >> 4) * 8 + j;
        float v = 0.f;
        if (rB < DIM) {
            if (k < KZ) {
                if (k < N_BASES * DIM) {
                    int b = k / DIM, kc = k - b * DIM;
                    v = weight[(b * DIM + kc) * DIM + rB];
                }
            } else {
                int jj = k - KZ;
                if (jj < DIM) v = sw[jj * DIM + rB];
            }
        }
        BSW[idx] = f2bf(v);
        return;
    }
    idx -= PREP_B;
    if (idx < PREP_X) {
        int n = idx / 224, j = idx - n * 224;
        float v = (j < DIM) ? x[(size_t)n * DIM + j] : 0.f;
        if (j < DIM) Xbf[(size_t)n * DIM + j] = f2bf(v);
        int d = deg[n]; if (d < 1) d = 1;
        ASW[asw_idx(n, KZ + j)] = f2bf((float)d * v);
        return;
    }
    idx -= PREP_X;
    if (idx < PREP_O) {
        int c = idx % DIM;
        out[idx] = bias[c];
        return;
    }
    idx -= PREP_O;
    if (idx < PREP_C) {
        int t = idx >> 4, m = idx & 15;
        unsigned lo = f2bf(coeff[t * N_BASES + m]);
        unsigned hi = (m + 16 < N_BASES) ? f2bf(coeff[t * N_BASES + m + 16]) : 0u;
        Cpair[idx] = lo | (hi << 16);
    }
}

// ---------------- per-target-node aggregation via MFMA ----------------
// Z[n] (30x200) = C_n^T (30 x deg) @ X_n (deg x 200), K padded to 32 with A=0.
// Two-phase dump through 6.4 KB/wave LDS buffer into ASW v3 layout.

__global__ __launch_bounds__(256) void agg_kernel(const unsigned short* __restrict__ Xbf,
                                                  const unsigned int* __restrict__ Cpair,
                                                  const int* __restrict__ starts,
                                                  const int2* __restrict__ sedge,
                                                  unsigned short* __restrict__ ASW) {
    __shared__ __align__(16) unsigned short zbuf[4][3232];  // 25856 B/block
    int lane = threadIdx.x & 63;
    int wave = threadIdx.x >> 6;
    int n = blockIdx.x * 4 + wave;            // 2500*4 == 10000 exactly
    int ln = lane & 15, q = lane >> 4;

    floatx4 acc0[13], acc1[13];
#pragma unroll
    for (int f = 0; f < 13; ++f) {
        acc0[f] = (floatx4){0.f, 0.f, 0.f, 0.f};
        acc1[f] = acc0[f];
    }

    int e0 = starts[n], e1 = starts[n + 1];
    for (int kb = e0; kb < e1; kb += 32) {
        int eb = kb + 8 * q;
        unsigned short a0v[8], a1v[8];
        int srcs[8];
#pragma unroll
        for (int j = 0; j < 8; ++j) {
            int e = eb + j;
            int ec = (e < e1) ? e : (e1 - 1);
            int2 sd = sedge[ec];
            unsigned cp = (e < e1) ? Cpair[sd.y * 16 + ln] : 0u;
            a0v[j] = (unsigned short)(cp & 0xffffu);
            a1v[j] = (unsigned short)(cp >> 16);
            srcs[j] = sd.x;
        }
        short8 A0 = pack8(a0v), A1 = pack8(a1v);

        unsigned short bv[2][8];
#pragma unroll
        for (int j = 0; j < 8; ++j)
            bv[0][j] = Xbf[(size_t)srcs[j] * DIM + ln];
#pragma unroll
        for (int f = 0; f < 13; ++f) {
            int cur = f & 1, nxt = cur ^ 1;
            if (f < 12) {
#pragma unroll
                for (int j = 0; j < 8; ++j)
                    bv[nxt][j] = Xbf[(size_t)srcs[j] * DIM + (f + 1) * 16 + ln];
            }
            short8 B = pack8(bv[cur]);
            acc0[f] = __builtin_amdgcn_mfma_f32_16x16x32_bf16(A0, B, acc0[f], 0, 0, 0);
            acc1[f] = __builtin_amdgcn_mfma_f32_16x16x32_bf16(A1, B, acc1[f], 0, 0, 0);
        }
    }

    unsigned short* zb = zbuf[wave];
    int t = n >> 6, sub = (n >> 4) & 3, rl = n & 15;
    const uint4* zb4 = (const uint4*)zb;
    uint4* dst = (uint4*)ASW;
    size_t base_u4 = (size_t)t * NSTEPS * 256 + sub * 64 + rl * 4;

    // phase 1: bases 0..15 -> cols [0,3200), ksteps 0..99
#pragma unroll
    for (int f = 0; f < 13; ++f) {
        int d = f * 16 + ln;
        if (d < DIM) {
#pragma unroll
            for (int i = 0; i < 4; ++i)
                zb[(q * 4 + i) * DIM + d] = f2bf(acc0[f][i]);
        }
    }
    for (int v = lane; v < 400; v += 64) {
        int kk = v >> 2, w8 = v & 3;
        dst[base_u4 + (size_t)kk * 256 + w8] = zb4[v];
    }

    // phase 2: bases 16..29 -> cols [3200,6000) + pad, ksteps 100..187
    if (lane < 16) zb[2800 + lane] = 0;
#pragma unroll
    for (int f = 0; f < 13; ++f) {
        int d = f * 16 + ln;
        if (d < DIM) {
#pragma unroll
            for (int i = 0; i < 4; ++i) {
                int b1 = 16 + q * 4 + i;
                if (b1 < N_BASES) zb[(b1 - 16) * DIM + d] = f2bf(acc1[f][i]);
            }
        }
    }
    for (int v = lane; v < 352; v += 64) {
        int kk = 100 + (v >> 2), w8 = v & 3;
        dst[base_u4 + (size_t)kk * 256 + w8] = zb4[v];
    }
}

// ---------------- GEMM: out += dinv * (A_ext @ B_ext^T) over K-chunk ----------------
// Grid (157 tiles, 6 chunks). Block: 64 rows x 256 cols; wave w owns frags
// f = w + 4*i. Rotating two-register-set pipeline (no copies). Epilogue:
// per-row dinv scale + fp32 atomicAdd into out (pre-initialized with bias).

__global__ __launch_bounds__(256) void gemm_kernel(const unsigned short* __restrict__ ASW,
                                                   const unsigned short* __restrict__ BSW,
                                                   const float* __restrict__ dinv,
                                                   float* __restrict__ out) {
    int tid = threadIdx.x;
    int lane = tid & 63, wave = tid >> 6;
    int tile = blockIdx.x, chunk = blockIdx.y;
    int ks = (chunk * NSTEPS) / KSPLIT;
    int ke = ((chunk + 1) * NSTEPS) / KSPLIT;
    int ln = lane & 15, q = lane >> 4;

    const unsigned short* pa = ASW + (size_t)tile * NSTEPS * TKELEM + ln * 32 + q * 8;
    const unsigned short* pb = BSW + (size_t)(wave * NSTEPS) * 512 + lane * 8;

    floatx4 acc[4][4];   // [frag][sub]
#pragma unroll
    for (int i = 0; i < 4; ++i)
#pragma unroll
        for (int s = 0; s < 4; ++s) acc[i][s] = (floatx4){0.f, 0.f, 0.f, 0.f};

    short8 a0[4], b0[4], a1[4], b1[4];

    auto lda = [&](short8* dst, int k) {
#pragma unroll
        for (int s = 0; s < 4; ++s)
            dst[s] = *(const short8*)(pa + (size_t)k * TKELEM + s * 512);
    };
    auto ldb = [&](short8* dst, int k) {
#pragma unroll
        for (int i = 0; i < 4; ++i)
            dst[i] = *(const short8*)(pb + ((size_t)i * 4 * NSTEPS + k) * 512);
    };
    auto mfma16 = [&](short8* a, short8* b) {
#pragma unroll
        for (int i = 0; i < 4; ++i)
#pragma unroll
            for (int s = 0; s < 4; ++s)
                acc[i][s] = __builtin_amdgcn_mfma_f32_16x16x32_bf16(a[s], b[i], acc[i][s], 0, 0, 0);
    };

    lda(a0, ks); ldb(b0, ks);
    int k1 = (ks + 1 < ke) ? ks + 1 : ks;
    lda(a1, k1); ldb(b1, k1);

    int kk = ks;
    for (; kk + 2 < ke; kk += 2) {
        mfma16(a0, b0);
        lda(a0, kk + 2); ldb(b0, kk + 2);
        mfma16(a1, b1);
        int k3 = (kk + 3 < ke) ? kk + 3 : ke - 1;
        lda(a1, k3); ldb(b1, k3);
    }
    mfma16(a0, b0);
    if (kk + 1 < ke) mfma16(a1, b1);

    // epilogue: scale by dinv, atomic-accumulate into out
    int row0 = tile * 64;
    float dv[4][4];
    int nr[4][4];
#pragma unroll
    for (int s = 0; s < 4; ++s)
#pragma unroll
        for (int ii = 0; ii < 4; ++ii) {
            int n = row0 + s * 16 + q * 4 + ii;
            nr[s][ii] = n;
            dv[s][ii] = (n < N_NODES) ? dinv[n] : 0.f;
        }
#pragma unroll
    for (int i = 0; i < 4; ++i) {
        int fg = wave + 4 * i;
        int c = fg * 16 + ln;
        if (fg < 13 && c < DIM) {
#pragma unroll
            for (int s = 0; s < 4; ++s)
#pragma unroll
                for (int ii = 0; ii < 4; ++ii) {
                    int n = nr[s][ii];
                    if (n < N_NODES)
                        atomicAdd(&out[(size_t)n * DIM + c], acc[i][s][ii] * dv[s][ii]);
                }
        }
    }
}

// ---------------- launch ----------------

extern "C" void kernel_launch(void* const* d_in, const int* in_sizes, int n_in,
                              void* d_out, int out_size, void* d_ws, size_t ws_size,
                              hipStream_t stream) {
    const float* x      = (const float*)d_in[0];
    const float* weight = (const float*)d_in[1];
    const float* coeff  = (const float*)d_in[2];
    const float* selfw  = (const float*)d_in[3];
    const float* bias   = (const float*)d_in[4];
    const int*   eidx   = (const int*)d_in[5];
    const int*   etype  = (const int*)d_in[6];
    const int* src = eidx;
    const int* tgt = eidx + N_EDGES;
    float* out = (float*)d_out;

    char* ws = (char*)d_ws;
    size_t off = 0;
    auto carve = [&](size_t bytes) {
        char* p = ws + off;
        off += (bytes + 255) & ~(size_t)255;
        return p;
    };
    unsigned short* ASW  = (unsigned short*)carve((size_t)NTILES * NSTEPS * TKELEM * 2);  // 125.4 MB
    unsigned short* BSW  = (unsigned short*)carve((size_t)NFRAG * NSTEPS * 512 * 2);
    unsigned short* Xbf  = (unsigned short*)carve((size_t)(N_NODES * DIM + 64) * 2);
    unsigned int*  Cpair = (unsigned int*)carve((size_t)N_REL * 16 * 4);
    int*   deg    = (int*)carve((size_t)N_NODES * 4);
    int*   starts = (int*)carve((size_t)(N_NODES + 1) * 4);
    int*   cursor = (int*)carve((size_t)N_NODES * 4);
    float* dinv   = (float*)carve((size_t)N_NODES * 4);
    int2*  sedge  = (int2*)carve((size_t)N_EDGES * 8);

    hipMemsetAsync(deg, 0, (size_t)N_NODES * 4, stream);
    hist_kernel<<<(N_EDGES + 255) / 256, 256, 0, stream>>>(tgt, deg);
    scan_kernel<<<1, 1024, 0, stream>>>(deg, starts, cursor, dinv);
    scatter_kernel<<<(N_EDGES + 255) / 256, 256, 0, stream>>>(src, tgt, etype, cursor, sedge);

    prep_kernel<<<(PREP_TOTAL + 255) / 256, 256, 0, stream>>>(
        weight, selfw, x, coeff, bias, deg, BSW, Xbf, ASW, out, Cpair);

    agg_kernel<<<N_NODES / 4, 256, 0, stream>>>(Xbf, Cpair, starts, sedge, ASW);

    dim3 ggrid(NTILES, KSPLIT);
    gemm_kernel<<<ggrid, 256, 0, stream>>>(ASW, BSW, dinv, out);
}

// Round 17
// 258.293 us; speedup vs baseline: 1.1672x; 1.1672x over previous
//
#include <hip/hip_runtime.h>
#include <hip/hip_bf16.h>

#define N_NODES 10000
#define N_EDGES 320000
#define N_REL   460
#define N_BASES 30
#define DIM     200
#define KZ      6016   // 30*200=6000 padded to multiple of 32
#define KT      6240   // KZ + 224 (self-term columns appended)
#define NSTEPS  195    // KT/32
#define NTILES  157    // ceil(10000/64)
#define NFRAG   16     // col fragments of 16 (13 real, 3 zero-padded)
#define KSPLIT  6
#define PROWS   10048  // 157*64
#define TKELEM  2048   // ASW elements per (tile,kstep): 4 sub x 16 rows x 32 cols

#define PREP_B  (NFRAG * NSTEPS * 512)   // 1597440
#define PREP_C  (N_REL * 16)             // 7360
#define PREP_X  (N_NODES * 224)          // 2240000
#define S1_TOTAL (N_EDGES + PREP_B + PREP_C)
#define S2_TOTAL (N_EDGES + PREP_X)

using short8  = __attribute__((ext_vector_type(8))) short;
using floatx4 = __attribute__((ext_vector_type(4))) float;

__device__ __forceinline__ unsigned short f2bf(float f) {
    union { float f; unsigned u; } v; v.f = f;
    unsigned u = v.u;
    return (unsigned short)((u + 0x7fffu + ((u >> 16) & 1u)) >> 16);
}

__device__ __forceinline__ short8 pack8(const unsigned short* u) {
    union { unsigned short s[8]; short8 v; } p;
#pragma unroll
    for (int i = 0; i < 8; ++i) p.s[i] = u[i];
    return p.v;
}

// ASW v3: 64-row tiles. Element (node n, col c):
//   t=n>>6, sub=(n>>4)&3, rl=n&15; kk=c>>5, w=c&31
//   idx = (t*195+kk)*2048 + sub*512 + rl*32 + w
__device__ __forceinline__ size_t asw_idx(int n, int c) {
    int t = n >> 6, sub = (n >> 4) & 3, rl = n & 15;
    int kk = c >> 5, w = c & 31;
    return (size_t)(t * NSTEPS + kk) * TKELEM + sub * 512 + rl * 32 + w;
}

// ---------------- sort phase 1: hist + independent prep (B, Cpair) ----------------

__global__ void sort1_kernel(const int* __restrict__ tgt, int* __restrict__ deg,
                             const float* __restrict__ weight, const float* __restrict__ sw,
                             const float* __restrict__ coeff,
                             unsigned short* __restrict__ BSW, unsigned int* __restrict__ Cpair) {
    int idx = blockIdx.x * blockDim.x + threadIdx.x;
    if (idx < N_EDGES) {
        atomicAdd(&deg[tgt[idx]], 1);
        return;
    }
    idx -= N_EDGES;
    if (idx < PREP_B) {
        int f = idx / (NSTEPS * 512);
        int rem = idx - f * (NSTEPS * 512);
        int kk = rem / 512;
        int e = rem - kk * 512;
        int l = e >> 3, j = e & 7;
        int rB = f * 16 + (l & 15);
        int k  = kk * 32 + (l >> 4) * 8 + j;
        float v = 0.f;
        if (rB < DIM) {
            if (k < KZ) {
                if (k < N_BASES * DIM) {
                    int b = k / DIM, kc = k - b * DIM;
                    v = weight[(b * DIM + kc) * DIM + rB];
                }
            } else {
                int jj = k - KZ;
                if (jj < DIM) v = sw[jj * DIM + rB];
            }
        }
        BSW[idx] = f2bf(v);
        return;
    }
    idx -= PREP_B;
    if (idx < PREP_C) {
        int t = idx >> 4, m = idx & 15;
        unsigned lo = f2bf(coeff[t * N_BASES + m]);
        unsigned hi = (m + 16 < N_BASES) ? f2bf(coeff[t * N_BASES + m + 16]) : 0u;
        Cpair[idx] = lo | (hi << 16);
    }
}

__global__ __launch_bounds__(1024) void scan_kernel(const int* deg, int* starts,
                                                    int* cursor, float* dinv) {
    __shared__ int part[1024];
    int tid = threadIdx.x;
    const int PER = (N_NODES + 1023) / 1024;  // 10
    int base = tid * PER;
    int s = 0;
    for (int i = 0; i < PER; ++i) { int idx = base + i; if (idx < N_NODES) s += deg[idx]; }
    part[tid] = s; __syncthreads();
    for (int off = 1; off < 1024; off <<= 1) {
        int v = (tid >= off) ? part[tid - off] : 0;
        __syncthreads();
        part[tid] += v;
        __syncthreads();
    }
    int run = (tid > 0) ? part[tid - 1] : 0;
    for (int i = 0; i < PER; ++i) {
        int idx = base + i;
        if (idx < N_NODES) {
            int d = deg[idx];
            starts[idx] = run; cursor[idx] = run;
            dinv[idx] = 1.0f / (float)(d > 0 ? d : 1);
            run += d;
        }
    }
    if (tid == 1023) starts[N_NODES] = part[1023];
}

// ---------------- sort phase 2: scatter + deg-dependent prep (Xbf, ASW self) ----------------

__global__ void sort2_kernel(const int* __restrict__ src, const int* __restrict__ tgt,
                             const int* __restrict__ etype, int* __restrict__ cursor,
                             int2* __restrict__ sedge,
                             const float* __restrict__ x, const int* __restrict__ deg,
                             unsigned short* __restrict__ Xbf, unsigned short* __restrict__ ASW) {
    int idx = blockIdx.x * blockDim.x + threadIdx.x;
    if (idx < N_EDGES) {
        int t = tgt[idx];
        int pos = atomicAdd(&cursor[t], 1);
        sedge[pos] = make_int2(src[idx], etype[idx]);
        return;
    }
    idx -= N_EDGES;
    if (idx < PREP_X) {
        int n = idx / 224, j = idx - n * 224;
        float v = (j < DIM) ? x[(size_t)n * DIM + j] : 0.f;
        if (j < DIM) Xbf[(size_t)n * DIM + j] = f2bf(v);
        int d = deg[n]; if (d < 1) d = 1;
        ASW[asw_idx(n, KZ + j)] = f2bf((float)d * v);
    }
}

// ---------------- per-target-node aggregation via MFMA ----------------
// Z[n] (30x200) = C_n^T (30 x deg) @ X_n (deg x 200), K padded to 32 with A=0.
// Two-phase dump through 6.4 KB/wave LDS buffer into ASW v3 layout.

__global__ __launch_bounds__(256) void agg_kernel(const unsigned short* __restrict__ Xbf,
                                                  const unsigned int* __restrict__ Cpair,
                                                  const int* __restrict__ starts,
                                                  const int2* __restrict__ sedge,
                                                  unsigned short* __restrict__ ASW) {
    __shared__ __align__(16) unsigned short zbuf[4][3232];  // 25856 B/block
    int lane = threadIdx.x & 63;
    int wave = threadIdx.x >> 6;
    int n = blockIdx.x * 4 + wave;            // 2500*4 == 10000 exactly
    int ln = lane & 15, q = lane >> 4;

    floatx4 acc0[13], acc1[13];
#pragma unroll
    for (int f = 0; f < 13; ++f) {
        acc0[f] = (floatx4){0.f, 0.f, 0.f, 0.f};
        acc1[f] = acc0[f];
    }

    int e0 = starts[n], e1 = starts[n + 1];
    for (int kb = e0; kb < e1; kb += 32) {
        int eb = kb + 8 * q;
        unsigned short a0v[8], a1v[8];
        int srcs[8];
#pragma unroll
        for (int j = 0; j < 8; ++j) {
            int e = eb + j;
            int ec = (e < e1) ? e : (e1 - 1);
            int2 sd = sedge[ec];
            unsigned cp = (e < e1) ? Cpair[sd.y * 16 + ln] : 0u;
            a0v[j] = (unsigned short)(cp & 0xffffu);
            a1v[j] = (unsigned short)(cp >> 16);
            srcs[j] = sd.x;
        }
        short8 A0 = pack8(a0v), A1 = pack8(a1v);

        unsigned short bv[2][8];
#pragma unroll
        for (int j = 0; j < 8; ++j)
            bv[0][j] = Xbf[(size_t)srcs[j] * DIM + ln];
#pragma unroll
        for (int f = 0; f < 13; ++f) {
            int cur = f & 1, nxt = cur ^ 1;
            if (f < 12) {
#pragma unroll
                for (int j = 0; j < 8; ++j)
                    bv[nxt][j] = Xbf[(size_t)srcs[j] * DIM + (f + 1) * 16 + ln];
            }
            short8 B = pack8(bv[cur]);
            acc0[f] = __builtin_amdgcn_mfma_f32_16x16x32_bf16(A0, B, acc0[f], 0, 0, 0);
            acc1[f] = __builtin_amdgcn_mfma_f32_16x16x32_bf16(A1, B, acc1[f], 0, 0, 0);
        }
    }

    unsigned short* zb = zbuf[wave];
    int t = n >> 6, sub = (n >> 4) & 3, rl = n & 15;
    const uint4* zb4 = (const uint4*)zb;
    uint4* dst = (uint4*)ASW;
    size_t base_u4 = (size_t)t * NSTEPS * 256 + sub * 64 + rl * 4;

    // phase 1: bases 0..15 -> cols [0,3200), ksteps 0..99
#pragma unroll
    for (int f = 0; f < 13; ++f) {
        int d = f * 16 + ln;
        if (d < DIM) {
#pragma unroll
            for (int i = 0; i < 4; ++i)
                zb[(q * 4 + i) * DIM + d] = f2bf(acc0[f][i]);
        }
    }
    for (int v = lane; v < 400; v += 64) {
        int kk = v >> 2, w8 = v & 3;
        dst[base_u4 + (size_t)kk * 256 + w8] = zb4[v];
    }

    // phase 2: bases 16..29 -> cols [3200,6000) + pad, ksteps 100..187
    if (lane < 16) zb[2800 + lane] = 0;
#pragma unroll
    for (int f = 0; f < 13; ++f) {
        int d = f * 16 + ln;
        if (d < DIM) {
#pragma unroll
            for (int i = 0; i < 4; ++i) {
                int b1 = 16 + q * 4 + i;
                if (b1 < N_BASES) zb[(b1 - 16) * DIM + d] = f2bf(acc1[f][i]);
            }
        }
    }
    for (int v = lane; v < 352; v += 64) {
        int kk = 100 + (v >> 2), w8 = v & 3;
        dst[base_u4 + (size_t)kk * 256 + w8] = zb4[v];
    }
}

// ---------------- GEMM: part[chunk] = A_ext @ B_ext^T over K-chunk ----------------
// Grid (157 tiles, 6 chunks). Block: 64 rows x 256 cols; wave w owns frags
// f = w + 4*i. Rotating two-register-set pipeline: no copies, loads always
// one full body ahead. fp32 partials (R14 config — best measured).

__global__ __launch_bounds__(256) void gemm_kernel(const unsigned short* __restrict__ ASW,
                                                   const unsigned short* __restrict__ BSW,
                                                   float* __restrict__ part) {
    int tid = threadIdx.x;
    int lane = tid & 63, wave = tid >> 6;
    int tile = blockIdx.x, chunk = blockIdx.y;
    int ks = (chunk * NSTEPS) / KSPLIT;
    int ke = ((chunk + 1) * NSTEPS) / KSPLIT;
    int ln = lane & 15, q = lane >> 4;

    const unsigned short* pa = ASW + (size_t)tile * NSTEPS * TKELEM + ln * 32 + q * 8;
    const unsigned short* pb = BSW + (size_t)(wave * NSTEPS) * 512 + lane * 8;

    floatx4 acc[4][4];   // [frag][sub]
#pragma unroll
    for (int i = 0; i < 4; ++i)
#pragma unroll
        for (int s = 0; s < 4; ++s) acc[i][s] = (floatx4){0.f, 0.f, 0.f, 0.f};

    short8 a0[4], b0[4], a1[4], b1[4];

    auto lda = [&](short8* dst, int k) {
#pragma unroll
        for (int s = 0; s < 4; ++s)
            dst[s] = *(const short8*)(pa + (size_t)k * TKELEM + s * 512);
    };
    auto ldb = [&](short8* dst, int k) {
#pragma unroll
        for (int i = 0; i < 4; ++i)
            dst[i] = *(const short8*)(pb + ((size_t)i * 4 * NSTEPS + k) * 512);
    };
    auto mfma16 = [&](short8* a, short8* b) {
#pragma unroll
        for (int i = 0; i < 4; ++i)
#pragma unroll
            for (int s = 0; s < 4; ++s)
                acc[i][s] = __builtin_amdgcn_mfma_f32_16x16x32_bf16(a[s], b[i], acc[i][s], 0, 0, 0);
    };

    lda(a0, ks); ldb(b0, ks);
    int k1 = (ks + 1 < ke) ? ks + 1 : ks;
    lda(a1, k1); ldb(b1, k1);

    int kk = ks;
    for (; kk + 2 < ke; kk += 2) {
        mfma16(a0, b0);
        lda(a0, kk + 2); ldb(b0, kk + 2);
        mfma16(a1, b1);
        int k3 = (kk + 3 < ke) ? kk + 3 : ke - 1;
        lda(a1, k3); ldb(b1, k3);
    }
    mfma16(a0, b0);
    if (kk + 1 < ke) mfma16(a1, b1);

    int row0 = tile * 64;
    float* pbase = part + ((size_t)chunk * PROWS + row0) * 208;
#pragma unroll
    for (int i = 0; i < 4; ++i) {
        int fg = wave + 4 * i;
        if (fg < 13) {
            int c = fg * 16 + ln;
#pragma unroll
            for (int s = 0; s < 4; ++s)
#pragma unroll
                for (int ii = 0; ii < 4; ++ii)
                    pbase[(s * 16 + q * 4 + ii) * 208 + c] = acc[i][s][ii];
        }
    }
}

// ---------------- reduce: out = dinv * sum(partials) + bias ----------------

__global__ __launch_bounds__(256) void reduce_kernel(const float* __restrict__ part,
                                                     const float* __restrict__ dinv,
                                                     const float* __restrict__ bias,
                                                     float* __restrict__ out) {
    int idx = blockIdx.x * blockDim.x + threadIdx.x;
    if (idx >= N_NODES * 50) return;
    int r = idx / 50, cq = idx - r * 50;
    float4 s = {0.f, 0.f, 0.f, 0.f};
#pragma unroll
    for (int c = 0; c < KSPLIT; ++c) {
        float4 v = *(const float4*)(part + ((size_t)c * PROWS + r) * 208 + cq * 4);
        s.x += v.x; s.y += v.y; s.z += v.z; s.w += v.w;
    }
    float dv = dinv[r];
    float4 b = *(const float4*)(bias + cq * 4);
    float4 o;
    o.x = s.x * dv + b.x; o.y = s.y * dv + b.y;
    o.z = s.z * dv + b.z; o.w = s.w * dv + b.w;
    *(float4*)(out + (size_t)r * DIM + cq * 4) = o;
}

// ---------------- launch ----------------

extern "C" void kernel_launch(void* const* d_in, const int* in_sizes, int n_in,
                              void* d_out, int out_size, void* d_ws, size_t ws_size,
                              hipStream_t stream) {
    const float* x      = (const float*)d_in[0];
    const float* weight = (const float*)d_in[1];
    const float* coeff  = (const float*)d_in[2];
    const float* selfw  = (const float*)d_in[3];
    const float* bias   = (const float*)d_in[4];
    const int*   eidx   = (const int*)d_in[5];
    const int*   etype  = (const int*)d_in[6];
    const int* src = eidx;
    const int* tgt = eidx + N_EDGES;
    float* out = (float*)d_out;

    char* ws = (char*)d_ws;
    size_t off = 0;
    auto carve = [&](size_t bytes) {
        char* p = ws + off;
        off += (bytes + 255) & ~(size_t)255;
        return p;
    };
    unsigned short* ASW  = (unsigned short*)carve((size_t)NTILES * NSTEPS * TKELEM * 2);  // 125.4 MB
    unsigned short* BSW  = (unsigned short*)carve((size_t)NFRAG * NSTEPS * 512 * 2);
    float* part   = (float*)carve((size_t)KSPLIT * PROWS * 208 * 4);                      // 50.2 MB
    unsigned short* Xbf  = (unsigned short*)carve((size_t)(N_NODES * DIM + 64) * 2);
    unsigned int*  Cpair = (unsigned int*)carve((size_t)N_REL * 16 * 4);
    int*   deg    = (int*)carve((size_t)N_NODES * 4);
    int*   starts = (int*)carve((size_t)(N_NODES + 1) * 4);
    int*   cursor = (int*)carve((size_t)N_NODES * 4);
    float* dinv   = (float*)carve((size_t)N_NODES * 4);
    int2*  sedge  = (int2*)carve((size_t)N_EDGES * 8);

    hipMemsetAsync(deg, 0, (size_t)N_NODES * 4, stream);

    sort1_kernel<<<(S1_TOTAL + 255) / 256, 256, 0, stream>>>(
        tgt, deg, weight, selfw, coeff, BSW, Cpair);

    scan_kernel<<<1, 1024, 0, stream>>>(deg, starts, cursor, dinv);

    sort2_kernel<<<(S2_TOTAL + 255) / 256, 256, 0, stream>>>(
        src, tgt, etype, cursor, sedge, x, deg, Xbf, ASW);

    agg_kernel<<<N_NODES / 4, 256, 0, stream>>>(Xbf, Cpair, starts, sedge, ASW);

    dim3 ggrid(NTILES, KSPLIT);
    gemm_kernel<<<ggrid, 256, 0, stream>>>(ASW, BSW, part);

    reduce_kernel<<<(N_NODES * 50 + 255) / 256, 256, 0, stream>>>(part, dinv, bias, out);
}